// Round 2
// baseline (454.583 us; speedup 1.0000x reference)
//
#include <hip/hip_runtime.h>
#include <hip/hip_bf16.h>
#include <math.h>

#define N_NODES 40000
#define NE      640000
#define FIN     33
#define H       128
#define COUT    3
#define NLAYERS 8
#define ALPHA   0.1f
#define THETA   0.5f
#define CAP     96             // max bucket capacity; deg ~ Poisson(16), P(>96) ~ 1e-40

// setup mega-kernel block ranges: long-pole branch (xin, 2500 blocks) first
#define SB_XIN  2500           // xin:     2500 blocks * 16 nodes = 40000
#define SB_SCAT 1250           // scatter: 1250 blocks * 256 thr * 2 edges = 640000
#define SB_WPRE 512            // wprep:   512 blocks * 256 = 131072 elements

typedef __bf16 bf16x8 __attribute__((ext_vector_type(8)));
typedef float  f32x4  __attribute__((ext_vector_type(4)));

__device__ inline unsigned short f2bf(float f) {
    __hip_bfloat16 b = __float2bfloat16(f);
    return *(unsigned short*)&b;
}
__device__ inline float bf2f(unsigned short u) {
    __hip_bfloat16 b = *(__hip_bfloat16*)&u;
    return __bfloat162float(b);
}

// ---- setup mega-kernel: [xin | scatter | wprep(W-fold)] by block range ----
// xin first: it has the most blocks (2500), so starting it first minimizes
// the dispatch makespan; scatter (latency-bound) overlaps xin's bulk.
__global__ __launch_bounds__(256) void k_setup(
        const int* __restrict__ row, const int* __restrict__ col,
        const float* __restrict__ w, int* __restrict__ cnt,
        unsigned int* __restrict__ bucket,
        const float* __restrict__ Wconv, unsigned short* __restrict__ Wtbf,
        const float* __restrict__ x, const float* __restrict__ Win,
        const float* __restrict__ bin,
        unsigned short* __restrict__ x0bf) {
    __shared__ float sW[H * FIN];      // used by xin branch only (16.9 KB)
    __shared__ float sx[16][FIN];
    int b = blockIdx.x, t = threadIdx.x;

    if (b < SB_XIN) {
        // x0 = relu(x @ W_in^T + b_in) -> bf16
        int n0 = b * 16;
        for (int i = t; i < H * FIN; i += 256) sW[i] = Win[i];
        for (int i = t; i < 16 * FIN; i += 256)
            sx[i / FIN][i % FIN] = x[(size_t)(n0 + i / FIN) * FIN + (i % FIN)];
        __syncthreads();
        int f = t % H;
        int l0 = t / H;
        float bv = bin[f];
        for (int lo = l0; lo < 16; lo += 2) {
            float acc = bv;
            #pragma unroll
            for (int k = 0; k < FIN; k++) acc += sx[lo][k] * sW[f * FIN + k];
            acc = fmaxf(acc, 0.f);
            x0bf[(size_t)(n0 + lo) * H + f] = f2bf(acc);
        }
        return;
    }
    if (b < SB_XIN + SB_SCAT) {
        // bucket scatter: 2 independent chains/thread (more waves -> more TLP
        // to hide atomic round-trip); record = [bf16 w | col]
        int e0 = ((b - SB_XIN) * 256 + t) * 2;
        int r[2], pos[2];
        unsigned int rec[2];
        #pragma unroll
        for (int i = 0; i < 2; i++) {
            int e = e0 + i;
            r[i] = row[e];
            unsigned int wb = f2bf((1.0f - ALPHA) * w[e]);
            rec[i] = (wb << 16) | (unsigned int)col[e];
        }
        #pragma unroll
        for (int i = 0; i < 2; i++) pos[i] = atomicAdd(&cnt[r[i]], 1);
        #pragma unroll
        for (int i = 0; i < 2; i++) bucket[(size_t)r[i] * CAP + pos[i]] = rec[i];
        return;
    }
    {
        // W' = (1-beta)*I + beta*W, transposed to [l][j][k], bf16.
        int idx = (b - SB_XIN - SB_SCAT) * 256 + t;   // = l*16384 + k*128 + j
        int l = idx >> 14;
        int rem = idx & 16383;
        int k = rem >> 7, j = rem & 127;
        float beta = logf(THETA / (float)(l + 1) + 1.0f);
        float v = beta * Wconv[idx];
        if (j == k) v += 1.0f - beta;
        Wtbf[l * 16384 + j * 128 + k] = f2bf(v);
    }
}

// ---- fused layer: spmm -> LDS -> MFMA GEMM -> residual/store (coalesced) --
// block = 256 thr (4 waves), 32 rows. h double-buffered (hin read-only, hout
// write-only) so the fusion has no intra-dispatch read/write race.
// Phase 1: wave w computes xx rows w*8..w*8+7, ROW-PAIRED: two rows' full
//          dependency chains (bucket load -> gather -> fma -> reduce) in
//          flight simultaneously for latency hiding. Masked tail slots
//          gather hin row 0 (uniform per 16-lane group -> 1 L1-hit line).
// Phase 2: 4 waves split 32x128 output: rows (wv>>1)*16, cols (wv&1)*64;
//          16 MFMAs/wave from LDS A-frags + global Wt B-frags.
// Phase 3: acc -> LDS fp32, then cooperative coalesced epilogue: uint4 loads
//          of hin, residual+relu, uint4 stores of hout (or out-projection).
__global__ __launch_bounds__(256) void k_layer(
        const int* __restrict__ cnt, const unsigned int* __restrict__ bucket,
        const unsigned short* __restrict__ hin,
        const unsigned short* __restrict__ x0bf,
        const unsigned short* __restrict__ Wt,
        unsigned short* __restrict__ hout,
        const float* __restrict__ Wout, const float* __restrict__ bout,
        float* __restrict__ out, int do_out) {
    __shared__ __align__(16) char smem[16896];   // union: bf16 xx[32][136] / f32 acc[32][132]

    int t = threadIdx.x;
    int wv = t >> 6, lane = t & 63;
    int rbase = blockIdx.x * 32;

    // ---------------- phase 1: spmm into LDS (row-paired) ----------------
    {
        int slot = lane >> 4;              // 0..3: edge within a group of 4
        int fid  = lane & 15;              // feature block: features fid*8..+7
        int rb = wv * 8;
        #pragma unroll 1
        for (int i = 0; i < 8; i += 2) {
            int rlocA = rb + i, rlocB = rb + i + 1;
            int rowA = rbase + rlocA, rowB = rbase + rlocB;
            int dA = cnt[rowA], dB = cnt[rowB];
            const unsigned int* epA = bucket + (size_t)rowA * CAP;
            const unsigned int* epB = bucket + (size_t)rowB * CAP;
            float aA[8] = {0,0,0,0,0,0,0,0};
            float aB[8] = {0,0,0,0,0,0,0,0};
            int dmax = dA > dB ? dA : dB;

            for (int e = 0; e < dmax; e += 16) {
                unsigned int uA[4], uB[4];
                uint4 qA[4], qB[4];
                #pragma unroll
                for (int k = 0; k < 4; k++) {
                    int ei = e + k * 4 + slot;           // < CAP always
                    unsigned int ua = epA[ei];
                    unsigned int ub = epB[ei];
                    uA[k] = (ei < dA) ? ua : 0u;
                    uB[k] = (ei < dB) ? ub : 0u;
                }
                #pragma unroll
                for (int k = 0; k < 4; k++) {
                    qA[k] = *(const uint4*)(hin + (size_t)(uA[k] & 0xffffu) * H + fid * 8);
                    qB[k] = *(const uint4*)(hin + (size_t)(uB[k] & 0xffffu) * H + fid * 8);
                }
                #pragma unroll
                for (int k = 0; k < 4; k++) {
                    float wa = bf2f((unsigned short)(uA[k] >> 16));
                    aA[0] += wa * bf2f((unsigned short)(qA[k].x & 0xffffu));
                    aA[1] += wa * bf2f((unsigned short)(qA[k].x >> 16));
                    aA[2] += wa * bf2f((unsigned short)(qA[k].y & 0xffffu));
                    aA[3] += wa * bf2f((unsigned short)(qA[k].y >> 16));
                    aA[4] += wa * bf2f((unsigned short)(qA[k].z & 0xffffu));
                    aA[5] += wa * bf2f((unsigned short)(qA[k].z >> 16));
                    aA[6] += wa * bf2f((unsigned short)(qA[k].w & 0xffffu));
                    aA[7] += wa * bf2f((unsigned short)(qA[k].w >> 16));
                    float wb = bf2f((unsigned short)(uB[k] >> 16));
                    aB[0] += wb * bf2f((unsigned short)(qB[k].x & 0xffffu));
                    aB[1] += wb * bf2f((unsigned short)(qB[k].x >> 16));
                    aB[2] += wb * bf2f((unsigned short)(qB[k].y & 0xffffu));
                    aB[3] += wb * bf2f((unsigned short)(qB[k].y >> 16));
                    aB[4] += wb * bf2f((unsigned short)(qB[k].z & 0xffffu));
                    aB[5] += wb * bf2f((unsigned short)(qB[k].z >> 16));
                    aB[6] += wb * bf2f((unsigned short)(qB[k].w & 0xffffu));
                    aB[7] += wb * bf2f((unsigned short)(qB[k].w >> 16));
                }
            }
            #pragma unroll
            for (int j = 0; j < 8; j++) {
                aA[j] += __shfl_xor(aA[j], 16);
                aA[j] += __shfl_xor(aA[j], 32);
                aB[j] += __shfl_xor(aB[j], 16);
                aB[j] += __shfl_xor(aB[j], 32);
            }
            if (slot == 0) {               // lanes 0..15 hold the full rows
                uint4 xqA = *(const uint4*)(x0bf + (size_t)rowA * H + fid * 8);
                uint4 xqB = *(const uint4*)(x0bf + (size_t)rowB * H + fid * 8);
                uint4 rA, rB;
                rA.x = (unsigned int)f2bf(aA[0] + ALPHA * bf2f((unsigned short)(xqA.x & 0xffffu)))
                     | ((unsigned int)f2bf(aA[1] + ALPHA * bf2f((unsigned short)(xqA.x >> 16))) << 16);
                rA.y = (unsigned int)f2bf(aA[2] + ALPHA * bf2f((unsigned short)(xqA.y & 0xffffu)))
                     | ((unsigned int)f2bf(aA[3] + ALPHA * bf2f((unsigned short)(xqA.y >> 16))) << 16);
                rA.z = (unsigned int)f2bf(aA[4] + ALPHA * bf2f((unsigned short)(xqA.z & 0xffffu)))
                     | ((unsigned int)f2bf(aA[5] + ALPHA * bf2f((unsigned short)(xqA.z >> 16))) << 16);
                rA.w = (unsigned int)f2bf(aA[6] + ALPHA * bf2f((unsigned short)(xqA.w & 0xffffu)))
                     | ((unsigned int)f2bf(aA[7] + ALPHA * bf2f((unsigned short)(xqA.w >> 16))) << 16);
                rB.x = (unsigned int)f2bf(aB[0] + ALPHA * bf2f((unsigned short)(xqB.x & 0xffffu)))
                     | ((unsigned int)f2bf(aB[1] + ALPHA * bf2f((unsigned short)(xqB.x >> 16))) << 16);
                rB.y = (unsigned int)f2bf(aB[2] + ALPHA * bf2f((unsigned short)(xqB.y & 0xffffu)))
                     | ((unsigned int)f2bf(aB[3] + ALPHA * bf2f((unsigned short)(xqB.y >> 16))) << 16);
                rB.z = (unsigned int)f2bf(aB[4] + ALPHA * bf2f((unsigned short)(xqB.z & 0xffffu)))
                     | ((unsigned int)f2bf(aB[5] + ALPHA * bf2f((unsigned short)(xqB.z >> 16))) << 16);
                rB.w = (unsigned int)f2bf(aB[6] + ALPHA * bf2f((unsigned short)(xqB.w & 0xffffu)))
                     | ((unsigned int)f2bf(aB[7] + ALPHA * bf2f((unsigned short)(xqB.w >> 16))) << 16);
                *(uint4*)(smem + (size_t)rlocA * 272 + fid * 16) = rA;
                *(uint4*)(smem + (size_t)rlocB * 272 + fid * 16) = rB;
            }
        }
    }
    __syncthreads();

    // ---------------- phase 2: MFMA GEMM from LDS ----------------
    int quad = lane >> 4, l16 = lane & 15;
    int rh = (wv >> 1) * 16;               // row half of this wave
    int ch = (wv & 1) * 64;                // col half of this wave
    f32x4 acc2[4];
    #pragma unroll
    for (int j = 0; j < 4; j++) acc2[j] = (f32x4){0.f, 0.f, 0.f, 0.f};

    #pragma unroll
    for (int k0 = 0; k0 < 4; k0++) {
        bf16x8 av = *(const bf16x8*)(smem + (size_t)(rh + l16) * 272 + k0 * 64 + quad * 16);
        #pragma unroll
        for (int j = 0; j < 4; j++) {
            bf16x8 bv = *(const bf16x8*)(Wt + (size_t)(ch + j * 16 + l16) * H + k0 * 32 + quad * 8);
            acc2[j] = __builtin_amdgcn_mfma_f32_16x16x32_bf16(av, bv, acc2[j], 0, 0, 0);
        }
    }
    __syncthreads();                       // all A-frag reads done; smem reusable

    // ---------------- phase 3a: acc -> LDS fp32 ----------------
    float* facc = (float*)smem;
    #pragma unroll
    for (int j = 0; j < 4; j++) {
        #pragma unroll
        for (int r = 0; r < 4; r++)
            facc[(rh + quad * 4 + r) * 132 + ch + j * 16 + l16] = acc2[j][r];
    }
    __syncthreads();

    // ---------------- phase 3b: coalesced epilogue ----------------
    // thread t handles cols (t&15)*8..+7 of rows (t>>4) and (t>>4)+16
    int cb = (t & 15) * 8;
    #pragma unroll
    for (int p = 0; p < 2; p++) {
        int rloc = p * 16 + (t >> 4);
        int row  = rbase + rloc;
        const float* fr = facc + rloc * 132 + cb;
        f32x4 a0 = *(const f32x4*)fr;
        f32x4 a1 = *(const f32x4*)(fr + 4);
        uint4 hq = *(const uint4*)(hin + (size_t)row * H + cb);
        float hv[8];
        hv[0] = bf2f((unsigned short)(hq.x & 0xffffu)) + fmaxf(a0[0], 0.f);
        hv[1] = bf2f((unsigned short)(hq.x >> 16))     + fmaxf(a0[1], 0.f);
        hv[2] = bf2f((unsigned short)(hq.y & 0xffffu)) + fmaxf(a0[2], 0.f);
        hv[3] = bf2f((unsigned short)(hq.y >> 16))     + fmaxf(a0[3], 0.f);
        hv[4] = bf2f((unsigned short)(hq.z & 0xffffu)) + fmaxf(a1[0], 0.f);
        hv[5] = bf2f((unsigned short)(hq.z >> 16))     + fmaxf(a1[1], 0.f);
        hv[6] = bf2f((unsigned short)(hq.w & 0xffffu)) + fmaxf(a1[2], 0.f);
        hv[7] = bf2f((unsigned short)(hq.w >> 16))     + fmaxf(a1[3], 0.f);

        if (!do_out) {
            uint4 rr;
            rr.x = (unsigned int)f2bf(hv[0]) | ((unsigned int)f2bf(hv[1]) << 16);
            rr.y = (unsigned int)f2bf(hv[2]) | ((unsigned int)f2bf(hv[3]) << 16);
            rr.z = (unsigned int)f2bf(hv[4]) | ((unsigned int)f2bf(hv[5]) << 16);
            rr.w = (unsigned int)f2bf(hv[6]) | ((unsigned int)f2bf(hv[7]) << 16);
            *(uint4*)(hout + (size_t)row * H + cb) = rr;
        } else {
            // last layer: out = h @ Wout^T + bout, reduced over 16 lanes/row
            float p0 = 0.f, p1 = 0.f, p2 = 0.f;
            #pragma unroll
            for (int i2 = 0; i2 < 8; i2++) {
                float h = hv[i2];
                p0 += h * Wout[cb + i2];
                p1 += h * Wout[H + cb + i2];
                p2 += h * Wout[2 * H + cb + i2];
            }
            #pragma unroll
            for (int off = 1; off < 16; off <<= 1) {
                p0 += __shfl_xor(p0, off);
                p1 += __shfl_xor(p1, off);
                p2 += __shfl_xor(p2, off);
            }
            if ((t & 15) == 0) {
                out[(size_t)row * 3 + 0] = p0 + bout[0];
                out[(size_t)row * 3 + 1] = p1 + bout[1];
                out[(size_t)row * 3 + 2] = p2 + bout[2];
            }
        }
    }
}

extern "C" void kernel_launch(void* const* d_in, const int* in_sizes, int n_in,
                              void* d_out, int out_size, void* d_ws, size_t ws_size,
                              hipStream_t stream) {
    const float* x     = (const float*)d_in[0];
    const int*   erow  = (const int*)  d_in[1];
    const int*   ecol  = (const int*)  d_in[2];
    const float* ew    = (const float*)d_in[3];
    const float* Win   = (const float*)d_in[4];
    const float* bin   = (const float*)d_in[5];
    const float* Wout  = (const float*)d_in[6];
    const float* bout  = (const float*)d_in[7];
    const float* Wconv = (const float*)d_in[8];
    float* out = (float*)d_out;

    char* ws = (char*)d_ws;
    const size_t NHb = (size_t)N_NODES * H * sizeof(unsigned short);  // 10,240,000
    unsigned short* x0bf  = (unsigned short*)(ws);
    unsigned short* bufA  = (unsigned short*)(ws + NHb);
    unsigned short* bufB  = (unsigned short*)(ws + 2 * NHb);
    char* p = ws + 3 * NHb;
    unsigned short* Wtbf  = (unsigned short*)p;  p += 8 * H * H * 2;  // 262,144
    int*  cnt     = (int*) p;  p += 160256;                           // N ints, padded
    unsigned int* bucket = (unsigned int*)p;     // N * CAP * 4 = 15,360,000 B

    // zero bucket counters, then one mega-dispatch: xin + scatter + W-fold
    hipMemsetAsync(cnt, 0, (size_t)N_NODES * 4, stream);
    k_setup<<<SB_XIN + SB_SCAT + SB_WPRE, 256, 0, stream>>>(
        erow, ecol, ew, cnt, bucket, Wconv, Wtbf, x, Win, bin, x0bf);

    // fused layers; h ping-pongs: x0 -> A -> B -> A -> ... (read/write
    // buffers disjoint each layer, so spmm gathers never race with stores)
    for (int l = 0; l < NLAYERS; l++) {
        const unsigned short* hin = (l == 0) ? x0bf : ((l & 1) ? bufA : bufB);
        unsigned short* hout = (l & 1) ? bufB : bufA;
        k_layer<<<N_NODES / 32, 256, 0, stream>>>(
            cnt, bucket, hin, x0bf, Wtbf + (size_t)l * H * H,
            hout, Wout, bout, out, (l == NLAYERS - 1) ? 1 : 0);
    }
}

// Round 3
// 418.690 us; speedup vs baseline: 1.0857x; 1.0857x over previous
//
#include <hip/hip_runtime.h>
#include <hip/hip_bf16.h>
#include <math.h>

#define N_NODES 40000
#define NE      640000
#define FIN     33
#define H       128
#define COUT    3
#define NLAYERS 8
#define ALPHA   0.1f
#define THETA   0.5f
#define CAP     96             // max bucket capacity; deg ~ Poisson(16), P(>96) ~ 1e-40
#define RPB     64             // rows per k_layer block

// setup mega-kernel block ranges (R0 order: scatter FIRST — longest
// per-block branch; LPT packing minimizes makespan)
#define SB_SCAT 625            // scatter: 625 blocks * 256 thr * 4 edges = 640000
#define SB_WPRE 512            // wprep:   512 blocks * 256 = 131072 elements
#define SB_XIN  2500           // xin:     2500 blocks * 16 nodes = 40000

typedef __bf16 bf16x8 __attribute__((ext_vector_type(8)));
typedef float  f32x4  __attribute__((ext_vector_type(4)));

__device__ inline unsigned short f2bf(float f) {
    __hip_bfloat16 b = __float2bfloat16(f);
    return *(unsigned short*)&b;
}
__device__ inline float bf2f(unsigned short u) {
    __hip_bfloat16 b = *(__hip_bfloat16*)&u;
    return __bfloat162float(b);
}

// ---- setup mega-kernel: [scatter | wprep(W-fold) | xin] by block range ----
__global__ __launch_bounds__(256) void k_setup(
        const int* __restrict__ row, const int* __restrict__ col,
        const float* __restrict__ w, int* __restrict__ cnt,
        unsigned int* __restrict__ bucket,
        const float* __restrict__ Wconv, unsigned short* __restrict__ Wtbf,
        const float* __restrict__ x, const float* __restrict__ Win,
        const float* __restrict__ bin,
        unsigned short* __restrict__ x0bf) {
    __shared__ float sW[H * FIN];      // used by xin branch only (16.9 KB)
    __shared__ float sx[16][FIN];
    int b = blockIdx.x, t = threadIdx.x;

    if (b < SB_SCAT) {
        // bucket scatter: 4 independent chains/thread; record = [bf16 w | col]
        int e0 = (b * 256 + t) * 4;
        int r[4], pos[4];
        unsigned int rec[4];
        #pragma unroll
        for (int i = 0; i < 4; i++) {
            int e = e0 + i;
            r[i] = row[e];
            unsigned int wb = f2bf((1.0f - ALPHA) * w[e]);
            rec[i] = (wb << 16) | (unsigned int)col[e];
        }
        #pragma unroll
        for (int i = 0; i < 4; i++) pos[i] = atomicAdd(&cnt[r[i]], 1);
        #pragma unroll
        for (int i = 0; i < 4; i++) bucket[(size_t)r[i] * CAP + pos[i]] = rec[i];
        return;
    }
    if (b < SB_SCAT + SB_WPRE) {
        // W' = (1-beta)*I + beta*W, transposed to [l][j][k], bf16.
        int idx = (b - SB_SCAT) * 256 + t;        // = l*16384 + k*128 + j
        int l = idx >> 14;
        int rem = idx & 16383;
        int k = rem >> 7, j = rem & 127;
        float beta = logf(THETA / (float)(l + 1) + 1.0f);
        float v = beta * Wconv[idx];
        if (j == k) v += 1.0f - beta;
        Wtbf[l * 16384 + j * 128 + k] = f2bf(v);
        return;
    }
    {
        // x0 = relu(x @ W_in^T + b_in) -> bf16
        int n0 = (b - SB_SCAT - SB_WPRE) * 16;
        for (int i = t; i < H * FIN; i += 256) sW[i] = Win[i];
        for (int i = t; i < 16 * FIN; i += 256)
            sx[i / FIN][i % FIN] = x[(size_t)(n0 + i / FIN) * FIN + (i % FIN)];
        __syncthreads();
        int f = t % H;
        int l0 = t / H;
        float bv = bin[f];
        for (int lo = l0; lo < 16; lo += 2) {
            float acc = bv;
            #pragma unroll
            for (int k = 0; k < FIN; k++) acc += sx[lo][k] * sW[f * FIN + k];
            acc = fmaxf(acc, 0.f);
            x0bf[(size_t)(n0 + lo) * H + f] = f2bf(acc);
        }
    }
}

// ---- fused layer: spmm -> LDS -> MFMA GEMM -> residual/store (coalesced) --
// block = 512 thr (8 waves), 64 rows: halves per-layer Wt B-fragment traffic
// (each block reads 2x the 32KB W' slice regardless of row count -> bigger
// tile amortizes it) and halves block count. LDS 33.8KB -> 4 blocks/CU
// (= 32 waves, full occupancy if VGPR<=64; launch_bounds guards spill).
// Phase 1: wave w computes xx rows w*8..w*8+7 (R0-proven serial-row form).
// Phase 2: 8 waves tile 64x128: rows (wv>>1)*16, cols (wv&1)*64.
// Phase 3: acc -> LDS fp32, then cooperative coalesced epilogue.
__global__ __launch_bounds__(512, 4) void k_layer(
        const int* __restrict__ cnt, const unsigned int* __restrict__ bucket,
        const unsigned short* __restrict__ hin,
        const unsigned short* __restrict__ x0bf,
        const unsigned short* __restrict__ Wt,
        unsigned short* __restrict__ hout,
        const float* __restrict__ Wout, const float* __restrict__ bout,
        float* __restrict__ out, int do_out) {
    __shared__ __align__(16) char smem[33792];   // bf16 xx[64][136] (17.4KB) / f32 acc[64][132] (33.8KB)

    int t = threadIdx.x;
    int wv = t >> 6, lane = t & 63;
    int rbase = blockIdx.x * RPB;

    // ---------------- phase 1: spmm into LDS ----------------
    {
        int slot = lane >> 4;              // 0..3: edge within a group of 4
        int fid  = lane & 15;              // feature block: features fid*8..+7
        for (int i = 0; i < 8; i++) {
            int rloc = wv * 8 + i;
            int row  = rbase + rloc;
            int deg  = cnt[row];
            const unsigned int* ep = bucket + (size_t)row * CAP;
            float acc[8] = {0,0,0,0,0,0,0,0};

            for (int e = 0; e < deg; e += 16) {
                unsigned int u[4];
                uint4 q[4];
                #pragma unroll
                for (int k = 0; k < 4; k++) {
                    int ei = e + k * 4 + slot;           // < CAP always
                    unsigned int uu = ep[ei];
                    u[k] = (ei < deg) ? uu : 0u;
                }
                #pragma unroll
                for (int k = 0; k < 4; k++)
                    q[k] = *(const uint4*)(hin + (size_t)(u[k] & 0xffffu) * H + fid * 8);
                #pragma unroll
                for (int k = 0; k < 4; k++) {
                    float w = bf2f((unsigned short)(u[k] >> 16));
                    acc[0] += w * bf2f((unsigned short)(q[k].x & 0xffffu));
                    acc[1] += w * bf2f((unsigned short)(q[k].x >> 16));
                    acc[2] += w * bf2f((unsigned short)(q[k].y & 0xffffu));
                    acc[3] += w * bf2f((unsigned short)(q[k].y >> 16));
                    acc[4] += w * bf2f((unsigned short)(q[k].z & 0xffffu));
                    acc[5] += w * bf2f((unsigned short)(q[k].z >> 16));
                    acc[6] += w * bf2f((unsigned short)(q[k].w & 0xffffu));
                    acc[7] += w * bf2f((unsigned short)(q[k].w >> 16));
                }
            }
            #pragma unroll
            for (int j = 0; j < 8; j++) {
                acc[j] += __shfl_xor(acc[j], 16);
                acc[j] += __shfl_xor(acc[j], 32);
            }
            if (slot == 0) {               // lanes 0..15 hold the full row
                uint4 xq = *(const uint4*)(x0bf + (size_t)row * H + fid * 8);
                float o0 = acc[0] + ALPHA * bf2f((unsigned short)(xq.x & 0xffffu));
                float o1 = acc[1] + ALPHA * bf2f((unsigned short)(xq.x >> 16));
                float o2 = acc[2] + ALPHA * bf2f((unsigned short)(xq.y & 0xffffu));
                float o3 = acc[3] + ALPHA * bf2f((unsigned short)(xq.y >> 16));
                float o4 = acc[4] + ALPHA * bf2f((unsigned short)(xq.z & 0xffffu));
                float o5 = acc[5] + ALPHA * bf2f((unsigned short)(xq.z >> 16));
                float o6 = acc[6] + ALPHA * bf2f((unsigned short)(xq.w & 0xffffu));
                float o7 = acc[7] + ALPHA * bf2f((unsigned short)(xq.w >> 16));
                uint4 r;
                r.x = (unsigned int)f2bf(o0) | ((unsigned int)f2bf(o1) << 16);
                r.y = (unsigned int)f2bf(o2) | ((unsigned int)f2bf(o3) << 16);
                r.z = (unsigned int)f2bf(o4) | ((unsigned int)f2bf(o5) << 16);
                r.w = (unsigned int)f2bf(o6) | ((unsigned int)f2bf(o7) << 16);
                *(uint4*)(smem + (size_t)rloc * 272 + fid * 16) = r;
            }
        }
    }
    __syncthreads();

    // ---------------- phase 2: MFMA GEMM from LDS ----------------
    int quad = lane >> 4, l16 = lane & 15;
    int rh = (wv >> 1) * 16;               // row group of this wave: 0/16/32/48
    int ch = (wv & 1) * 64;                // col half of this wave
    f32x4 acc2[4];
    #pragma unroll
    for (int j = 0; j < 4; j++) acc2[j] = (f32x4){0.f, 0.f, 0.f, 0.f};

    #pragma unroll
    for (int k0 = 0; k0 < 4; k0++) {
        bf16x8 av = *(const bf16x8*)(smem + (size_t)(rh + l16) * 272 + k0 * 64 + quad * 16);
        #pragma unroll
        for (int j = 0; j < 4; j++) {
            bf16x8 bv = *(const bf16x8*)(Wt + (size_t)(ch + j * 16 + l16) * H + k0 * 32 + quad * 8);
            acc2[j] = __builtin_amdgcn_mfma_f32_16x16x32_bf16(av, bv, acc2[j], 0, 0, 0);
        }
    }
    __syncthreads();                       // all A-frag reads done; smem reusable

    // ---------------- phase 3a: acc -> LDS fp32 ----------------
    float* facc = (float*)smem;
    #pragma unroll
    for (int j = 0; j < 4; j++) {
        #pragma unroll
        for (int r = 0; r < 4; r++)
            facc[(rh + quad * 4 + r) * 132 + ch + j * 16 + l16] = acc2[j][r];
    }
    __syncthreads();

    // ---------------- phase 3b: coalesced epilogue ----------------
    // thread t handles cols (t&15)*8..+7 of rows (t>>4) and (t>>4)+32
    int cb = (t & 15) * 8;
    #pragma unroll
    for (int p = 0; p < 2; p++) {
        int rloc = p * 32 + (t >> 4);
        int row  = rbase + rloc;
        const float* fr = facc + rloc * 132 + cb;
        f32x4 a0 = *(const f32x4*)fr;
        f32x4 a1 = *(const f32x4*)(fr + 4);
        uint4 hq = *(const uint4*)(hin + (size_t)row * H + cb);
        float hv[8];
        hv[0] = bf2f((unsigned short)(hq.x & 0xffffu)) + fmaxf(a0[0], 0.f);
        hv[1] = bf2f((unsigned short)(hq.x >> 16))     + fmaxf(a0[1], 0.f);
        hv[2] = bf2f((unsigned short)(hq.y & 0xffffu)) + fmaxf(a0[2], 0.f);
        hv[3] = bf2f((unsigned short)(hq.y >> 16))     + fmaxf(a0[3], 0.f);
        hv[4] = bf2f((unsigned short)(hq.z & 0xffffu)) + fmaxf(a1[0], 0.f);
        hv[5] = bf2f((unsigned short)(hq.z >> 16))     + fmaxf(a1[1], 0.f);
        hv[6] = bf2f((unsigned short)(hq.w & 0xffffu)) + fmaxf(a1[2], 0.f);
        hv[7] = bf2f((unsigned short)(hq.w >> 16))     + fmaxf(a1[3], 0.f);

        if (!do_out) {
            uint4 rr;
            rr.x = (unsigned int)f2bf(hv[0]) | ((unsigned int)f2bf(hv[1]) << 16);
            rr.y = (unsigned int)f2bf(hv[2]) | ((unsigned int)f2bf(hv[3]) << 16);
            rr.z = (unsigned int)f2bf(hv[4]) | ((unsigned int)f2bf(hv[5]) << 16);
            rr.w = (unsigned int)f2bf(hv[6]) | ((unsigned int)f2bf(hv[7]) << 16);
            *(uint4*)(hout + (size_t)row * H + cb) = rr;
        } else {
            // last layer: out = h @ Wout^T + bout, reduced over 16 lanes/row
            float p0 = 0.f, p1 = 0.f, p2 = 0.f;
            #pragma unroll
            for (int i2 = 0; i2 < 8; i2++) {
                float h = hv[i2];
                p0 += h * Wout[cb + i2];
                p1 += h * Wout[H + cb + i2];
                p2 += h * Wout[2 * H + cb + i2];
            }
            #pragma unroll
            for (int off = 1; off < 16; off <<= 1) {
                p0 += __shfl_xor(p0, off);
                p1 += __shfl_xor(p1, off);
                p2 += __shfl_xor(p2, off);
            }
            if ((t & 15) == 0) {
                out[(size_t)row * 3 + 0] = p0 + bout[0];
                out[(size_t)row * 3 + 1] = p1 + bout[1];
                out[(size_t)row * 3 + 2] = p2 + bout[2];
            }
        }
    }
}

extern "C" void kernel_launch(void* const* d_in, const int* in_sizes, int n_in,
                              void* d_out, int out_size, void* d_ws, size_t ws_size,
                              hipStream_t stream) {
    const float* x     = (const float*)d_in[0];
    const int*   erow  = (const int*)  d_in[1];
    const int*   ecol  = (const int*)  d_in[2];
    const float* ew    = (const float*)d_in[3];
    const float* Win   = (const float*)d_in[4];
    const float* bin   = (const float*)d_in[5];
    const float* Wout  = (const float*)d_in[6];
    const float* bout  = (const float*)d_in[7];
    const float* Wconv = (const float*)d_in[8];
    float* out = (float*)d_out;

    char* ws = (char*)d_ws;
    const size_t NHb = (size_t)N_NODES * H * sizeof(unsigned short);  // 10,240,000
    unsigned short* x0bf  = (unsigned short*)(ws);
    unsigned short* bufA  = (unsigned short*)(ws + NHb);
    unsigned short* bufB  = (unsigned short*)(ws + 2 * NHb);
    char* p = ws + 3 * NHb;
    unsigned short* Wtbf  = (unsigned short*)p;  p += 8 * H * H * 2;  // 262,144
    int*  cnt     = (int*) p;  p += 160256;                           // N ints, padded
    unsigned int* bucket = (unsigned int*)p;     // N * CAP * 4 = 15,360,000 B

    // zero bucket counters, then one mega-dispatch: scatter + W-fold + xin
    hipMemsetAsync(cnt, 0, (size_t)N_NODES * 4, stream);
    k_setup<<<SB_SCAT + SB_WPRE + SB_XIN, 256, 0, stream>>>(
        erow, ecol, ew, cnt, bucket, Wconv, Wtbf, x, Win, bin, x0bf);

    // fused layers; h ping-pongs: x0 -> A -> B -> A -> ... (read/write
    // buffers disjoint each layer, so spmm gathers never race with stores)
    for (int l = 0; l < NLAYERS; l++) {
        const unsigned short* hin = (l == 0) ? x0bf : ((l & 1) ? bufA : bufB);
        unsigned short* hout = (l & 1) ? bufB : bufA;
        k_layer<<<N_NODES / RPB, 512, 0, stream>>>(
            cnt, bucket, hin, x0bf, Wtbf + (size_t)l * H * H,
            hout, Wout, bout, out, (l == NLAYERS - 1) ? 1 : 0);
    }
}

// Round 4
// 404.581 us; speedup vs baseline: 1.1236x; 1.0349x over previous
//
#include <hip/hip_runtime.h>
#include <hip/hip_bf16.h>
#include <math.h>

#define N_NODES 40000
#define NE      640000
#define FIN     33
#define H       128
#define COUT    3
#define NLAYERS 8
#define ALPHA   0.1f
#define THETA   0.5f
#define CAP     96             // max bucket capacity; deg ~ Poisson(16), P(>96) ~ 1e-40
#define SREC    32             // staged records/row; P(deg>32) ~ 2e-4 -> global tail

// setup mega-kernel block ranges (scatter FIRST — longest per-block branch;
// LPT packing minimizes makespan; R1's xin-first order regressed 54->64us)
#define SB_SCAT 625            // scatter: 625 blocks * 256 thr * 4 edges = 640000
#define SB_WPRE 512            // wprep:   512 blocks * 256 = 131072 elements
#define SB_XIN  2500           // xin:     2500 blocks * 16 nodes = 40000

typedef __bf16 bf16x8 __attribute__((ext_vector_type(8)));
typedef float  f32x4  __attribute__((ext_vector_type(4)));

__device__ inline unsigned short f2bf(float f) {
    __hip_bfloat16 b = __float2bfloat16(f);
    return *(unsigned short*)&b;
}
__device__ inline float bf2f(unsigned short u) {
    __hip_bfloat16 b = *(__hip_bfloat16*)&u;
    return __bfloat162float(b);
}

// ---- setup mega-kernel: [scatter | wprep(W-fold) | xin] by block range ----
__global__ __launch_bounds__(256) void k_setup(
        const int* __restrict__ row, const int* __restrict__ col,
        const float* __restrict__ w, int* __restrict__ cnt,
        unsigned int* __restrict__ bucket,
        const float* __restrict__ Wconv, unsigned short* __restrict__ Wtbf,
        const float* __restrict__ x, const float* __restrict__ Win,
        const float* __restrict__ bin,
        unsigned short* __restrict__ x0bf) {
    __shared__ float sW[H * FIN];      // used by xin branch only (16.9 KB)
    __shared__ float sx[16][FIN];
    int b = blockIdx.x, t = threadIdx.x;

    if (b < SB_SCAT) {
        // bucket scatter: 4 independent chains/thread; record = [bf16 w | col]
        int e0 = (b * 256 + t) * 4;
        int r[4], pos[4];
        unsigned int rec[4];
        #pragma unroll
        for (int i = 0; i < 4; i++) {
            int e = e0 + i;
            r[i] = row[e];
            unsigned int wb = f2bf((1.0f - ALPHA) * w[e]);
            rec[i] = (wb << 16) | (unsigned int)col[e];
        }
        #pragma unroll
        for (int i = 0; i < 4; i++) pos[i] = atomicAdd(&cnt[r[i]], 1);
        #pragma unroll
        for (int i = 0; i < 4; i++) bucket[(size_t)r[i] * CAP + pos[i]] = rec[i];
        return;
    }
    if (b < SB_SCAT + SB_WPRE) {
        // W' = (1-beta)*I + beta*W, transposed to [l][j][k], bf16.
        int idx = (b - SB_SCAT) * 256 + t;        // = l*16384 + k*128 + j
        int l = idx >> 14;
        int rem = idx & 16383;
        int k = rem >> 7, j = rem & 127;
        float beta = logf(THETA / (float)(l + 1) + 1.0f);
        float v = beta * Wconv[idx];
        if (j == k) v += 1.0f - beta;
        Wtbf[l * 16384 + j * 128 + k] = f2bf(v);
        return;
    }
    {
        // x0 = relu(x @ W_in^T + b_in) -> bf16
        int n0 = (b - SB_SCAT - SB_WPRE) * 16;
        for (int i = t; i < H * FIN; i += 256) sW[i] = Win[i];
        for (int i = t; i < 16 * FIN; i += 256)
            sx[i / FIN][i % FIN] = x[(size_t)(n0 + i / FIN) * FIN + (i % FIN)];
        __syncthreads();
        int f = t % H;
        int l0 = t / H;
        float bv = bin[f];
        for (int lo = l0; lo < 16; lo += 2) {
            float acc = bv;
            #pragma unroll
            for (int k = 0; k < FIN; k++) acc += sx[lo][k] * sW[f * FIN + k];
            acc = fmaxf(acc, 0.f);
            x0bf[(size_t)(n0 + lo) * H + f] = f2bf(acc);
        }
    }
}

// ---- fused layer: spmm -> LDS -> MFMA GEMM -> residual/store (coalesced) --
// block = 256 thr (4 waves), 32 rows (R1-proven tile; 64-row regressed).
// Phase 1 (NEW): per wave, stage this wave's 8 rows' bucket records
//   (first 32 each, 4KB LDS total) + all 8 degrees UP-FRONT, then run a
//   fully-static row loop (2 masked 16-edge iterations/row). Removes the
//   bucket-load global round-trip from every row's critical path and lets
//   the compiler pipeline gathers across rows. deg>32 (P~2e-4): wave-uniform
//   global-read tail. Masked slots gather hin row 0 (L1-hit, ~free).
// Phase 2: 4 waves split 32x128: rows (wv>>1)*16, cols (wv&1)*64; 16 MFMAs.
// Phase 3: acc -> LDS fp32, then cooperative coalesced epilogue.
__global__ __launch_bounds__(256) void k_layer(
        const int* __restrict__ cnt, const unsigned int* __restrict__ bucket,
        const unsigned short* __restrict__ hin,
        const unsigned short* __restrict__ x0bf,
        const unsigned short* __restrict__ Wt,
        unsigned short* __restrict__ hout,
        const float* __restrict__ Wout, const float* __restrict__ bout,
        float* __restrict__ out, int do_out) {
    __shared__ __align__(16) char smem[16896];   // union: bf16 xx[32][136] / f32 acc[32][132]
    __shared__ unsigned int srec[4][8][SREC];    // staged bucket records (4 KB)

    int t = threadIdx.x;
    int wv = t >> 6, lane = t & 63;
    int rbase = blockIdx.x * 32;

    // ---------------- phase 1: spmm into LDS ----------------
    {
        int slot = lane >> 4;              // 0..3: edge within a group of 4
        int fid  = lane & 15;              // feature block: features fid*8..+7

        // stage: 8 rows x 32 records, 256 words, 4 coalesced rounds
        {
            const unsigned int* ep0 = bucket + (size_t)(rbase + wv * 8) * CAP;
            unsigned int* sl = &srec[wv][0][0];
            #pragma unroll
            for (int p = 0; p < 4; p++) {
                int idx = p * 64 + lane;
                int r = idx >> 5, c = idx & 31;
                sl[idx] = ep0[r * CAP + c];
            }
        }
        int degs[8];
        #pragma unroll
        for (int i = 0; i < 8; i++) degs[i] = cnt[rbase + wv * 8 + i];

        #pragma unroll
        for (int i = 0; i < 8; i++) {
            int rloc = wv * 8 + i;
            int row  = rbase + rloc;
            int deg  = degs[i];
            float acc[8] = {0,0,0,0,0,0,0,0};

            #pragma unroll
            for (int eb = 0; eb < 2; eb++) {   // static: covers deg <= 32
                unsigned int u[4];
                uint4 q[4];
                #pragma unroll
                for (int k = 0; k < 4; k++) {
                    int ei = eb * 16 + k * 4 + slot;
                    unsigned int uu = srec[wv][i][ei];
                    u[k] = (ei < deg) ? uu : 0u;
                }
                #pragma unroll
                for (int k = 0; k < 4; k++)
                    q[k] = *(const uint4*)(hin + (size_t)(u[k] & 0xffffu) * H + fid * 8);
                #pragma unroll
                for (int k = 0; k < 4; k++) {
                    float w = bf2f((unsigned short)(u[k] >> 16));
                    acc[0] += w * bf2f((unsigned short)(q[k].x & 0xffffu));
                    acc[1] += w * bf2f((unsigned short)(q[k].x >> 16));
                    acc[2] += w * bf2f((unsigned short)(q[k].y & 0xffffu));
                    acc[3] += w * bf2f((unsigned short)(q[k].y >> 16));
                    acc[4] += w * bf2f((unsigned short)(q[k].z & 0xffffu));
                    acc[5] += w * bf2f((unsigned short)(q[k].z >> 16));
                    acc[6] += w * bf2f((unsigned short)(q[k].w & 0xffffu));
                    acc[7] += w * bf2f((unsigned short)(q[k].w >> 16));
                }
            }

            if (deg > SREC) {              // wave-uniform rare tail (P ~ 2e-4)
                const unsigned int* ep = bucket + (size_t)row * CAP;
                for (int e = SREC; e < deg; e += 16) {
                    unsigned int u[4];
                    uint4 q[4];
                    #pragma unroll
                    for (int k = 0; k < 4; k++) {
                        int ei = e + k * 4 + slot;       // < CAP always
                        unsigned int uu = ep[ei];
                        u[k] = (ei < deg) ? uu : 0u;
                    }
                    #pragma unroll
                    for (int k = 0; k < 4; k++)
                        q[k] = *(const uint4*)(hin + (size_t)(u[k] & 0xffffu) * H + fid * 8);
                    #pragma unroll
                    for (int k = 0; k < 4; k++) {
                        float w = bf2f((unsigned short)(u[k] >> 16));
                        acc[0] += w * bf2f((unsigned short)(q[k].x & 0xffffu));
                        acc[1] += w * bf2f((unsigned short)(q[k].x >> 16));
                        acc[2] += w * bf2f((unsigned short)(q[k].y & 0xffffu));
                        acc[3] += w * bf2f((unsigned short)(q[k].y >> 16));
                        acc[4] += w * bf2f((unsigned short)(q[k].z & 0xffffu));
                        acc[5] += w * bf2f((unsigned short)(q[k].z >> 16));
                        acc[6] += w * bf2f((unsigned short)(q[k].w & 0xffffu));
                        acc[7] += w * bf2f((unsigned short)(q[k].w >> 16));
                    }
                }
            }

            #pragma unroll
            for (int j = 0; j < 8; j++) {
                acc[j] += __shfl_xor(acc[j], 16);
                acc[j] += __shfl_xor(acc[j], 32);
            }
            if (slot == 0) {               // lanes 0..15 hold the full row
                uint4 xq = *(const uint4*)(x0bf + (size_t)row * H + fid * 8);
                float o0 = acc[0] + ALPHA * bf2f((unsigned short)(xq.x & 0xffffu));
                float o1 = acc[1] + ALPHA * bf2f((unsigned short)(xq.x >> 16));
                float o2 = acc[2] + ALPHA * bf2f((unsigned short)(xq.y & 0xffffu));
                float o3 = acc[3] + ALPHA * bf2f((unsigned short)(xq.y >> 16));
                float o4 = acc[4] + ALPHA * bf2f((unsigned short)(xq.z & 0xffffu));
                float o5 = acc[5] + ALPHA * bf2f((unsigned short)(xq.z >> 16));
                float o6 = acc[6] + ALPHA * bf2f((unsigned short)(xq.w & 0xffffu));
                float o7 = acc[7] + ALPHA * bf2f((unsigned short)(xq.w >> 16));
                uint4 r;
                r.x = (unsigned int)f2bf(o0) | ((unsigned int)f2bf(o1) << 16);
                r.y = (unsigned int)f2bf(o2) | ((unsigned int)f2bf(o3) << 16);
                r.z = (unsigned int)f2bf(o4) | ((unsigned int)f2bf(o5) << 16);
                r.w = (unsigned int)f2bf(o6) | ((unsigned int)f2bf(o7) << 16);
                *(uint4*)(smem + (size_t)rloc * 272 + fid * 16) = r;
            }
        }
    }
    __syncthreads();

    // ---------------- phase 2: MFMA GEMM from LDS ----------------
    int quad = lane >> 4, l16 = lane & 15;
    int rh = (wv >> 1) * 16;               // row half of this wave
    int ch = (wv & 1) * 64;                // col half of this wave
    f32x4 acc2[4];
    #pragma unroll
    for (int j = 0; j < 4; j++) acc2[j] = (f32x4){0.f, 0.f, 0.f, 0.f};

    #pragma unroll
    for (int k0 = 0; k0 < 4; k0++) {
        bf16x8 av = *(const bf16x8*)(smem + (size_t)(rh + l16) * 272 + k0 * 64 + quad * 16);
        #pragma unroll
        for (int j = 0; j < 4; j++) {
            bf16x8 bv = *(const bf16x8*)(Wt + (size_t)(ch + j * 16 + l16) * H + k0 * 32 + quad * 8);
            acc2[j] = __builtin_amdgcn_mfma_f32_16x16x32_bf16(av, bv, acc2[j], 0, 0, 0);
        }
    }
    __syncthreads();                       // all A-frag reads done; smem reusable

    // ---------------- phase 3a: acc -> LDS fp32 ----------------
    float* facc = (float*)smem;
    #pragma unroll
    for (int j = 0; j < 4; j++) {
        #pragma unroll
        for (int r = 0; r < 4; r++)
            facc[(rh + quad * 4 + r) * 132 + ch + j * 16 + l16] = acc2[j][r];
    }
    __syncthreads();

    // ---------------- phase 3b: coalesced epilogue ----------------
    // thread t handles cols (t&15)*8..+7 of rows (t>>4) and (t>>4)+16
    int cb = (t & 15) * 8;
    #pragma unroll
    for (int p = 0; p < 2; p++) {
        int rloc = p * 16 + (t >> 4);
        int row  = rbase + rloc;
        const float* fr = facc + rloc * 132 + cb;
        f32x4 a0 = *(const f32x4*)fr;
        f32x4 a1 = *(const f32x4*)(fr + 4);
        uint4 hq = *(const uint4*)(hin + (size_t)row * H + cb);
        float hv[8];
        hv[0] = bf2f((unsigned short)(hq.x & 0xffffu)) + fmaxf(a0[0], 0.f);
        hv[1] = bf2f((unsigned short)(hq.x >> 16))     + fmaxf(a0[1], 0.f);
        hv[2] = bf2f((unsigned short)(hq.y & 0xffffu)) + fmaxf(a0[2], 0.f);
        hv[3] = bf2f((unsigned short)(hq.y >> 16))     + fmaxf(a0[3], 0.f);
        hv[4] = bf2f((unsigned short)(hq.z & 0xffffu)) + fmaxf(a1[0], 0.f);
        hv[5] = bf2f((unsigned short)(hq.z >> 16))     + fmaxf(a1[1], 0.f);
        hv[6] = bf2f((unsigned short)(hq.w & 0xffffu)) + fmaxf(a1[2], 0.f);
        hv[7] = bf2f((unsigned short)(hq.w >> 16))     + fmaxf(a1[3], 0.f);

        if (!do_out) {
            uint4 rr;
            rr.x = (unsigned int)f2bf(hv[0]) | ((unsigned int)f2bf(hv[1]) << 16);
            rr.y = (unsigned int)f2bf(hv[2]) | ((unsigned int)f2bf(hv[3]) << 16);
            rr.z = (unsigned int)f2bf(hv[4]) | ((unsigned int)f2bf(hv[5]) << 16);
            rr.w = (unsigned int)f2bf(hv[6]) | ((unsigned int)f2bf(hv[7]) << 16);
            *(uint4*)(hout + (size_t)row * H + cb) = rr;
        } else {
            // last layer: out = h @ Wout^T + bout, reduced over 16 lanes/row
            float p0 = 0.f, p1 = 0.f, p2 = 0.f;
            #pragma unroll
            for (int i2 = 0; i2 < 8; i2++) {
                float h = hv[i2];
                p0 += h * Wout[cb + i2];
                p1 += h * Wout[H + cb + i2];
                p2 += h * Wout[2 * H + cb + i2];
            }
            #pragma unroll
            for (int off = 1; off < 16; off <<= 1) {
                p0 += __shfl_xor(p0, off);
                p1 += __shfl_xor(p1, off);
                p2 += __shfl_xor(p2, off);
            }
            if ((t & 15) == 0) {
                out[(size_t)row * 3 + 0] = p0 + bout[0];
                out[(size_t)row * 3 + 1] = p1 + bout[1];
                out[(size_t)row * 3 + 2] = p2 + bout[2];
            }
        }
    }
}

extern "C" void kernel_launch(void* const* d_in, const int* in_sizes, int n_in,
                              void* d_out, int out_size, void* d_ws, size_t ws_size,
                              hipStream_t stream) {
    const float* x     = (const float*)d_in[0];
    const int*   erow  = (const int*)  d_in[1];
    const int*   ecol  = (const int*)  d_in[2];
    const float* ew    = (const float*)d_in[3];
    const float* Win   = (const float*)d_in[4];
    const float* bin   = (const float*)d_in[5];
    const float* Wout  = (const float*)d_in[6];
    const float* bout  = (const float*)d_in[7];
    const float* Wconv = (const float*)d_in[8];
    float* out = (float*)d_out;

    char* ws = (char*)d_ws;
    const size_t NHb = (size_t)N_NODES * H * sizeof(unsigned short);  // 10,240,000
    unsigned short* x0bf  = (unsigned short*)(ws);
    unsigned short* bufA  = (unsigned short*)(ws + NHb);
    unsigned short* bufB  = (unsigned short*)(ws + 2 * NHb);
    char* p = ws + 3 * NHb;
    unsigned short* Wtbf  = (unsigned short*)p;  p += 8 * H * H * 2;  // 262,144
    int*  cnt     = (int*) p;  p += 160256;                           // N ints, padded
    unsigned int* bucket = (unsigned int*)p;     // N * CAP * 4 = 15,360,000 B

    // zero bucket counters, then one mega-dispatch: scatter + W-fold + xin
    hipMemsetAsync(cnt, 0, (size_t)N_NODES * 4, stream);
    k_setup<<<SB_SCAT + SB_WPRE + SB_XIN, 256, 0, stream>>>(
        erow, ecol, ew, cnt, bucket, Wconv, Wtbf, x, Win, bin, x0bf);

    // fused layers; h ping-pongs: x0 -> A -> B -> A -> ... (read/write
    // buffers disjoint each layer, so spmm gathers never race with stores)
    for (int l = 0; l < NLAYERS; l++) {
        const unsigned short* hin = (l == 0) ? x0bf : ((l & 1) ? bufA : bufB);
        unsigned short* hout = (l & 1) ? bufB : bufA;
        k_layer<<<N_NODES / 32, 256, 0, stream>>>(
            cnt, bucket, hin, x0bf, Wtbf + (size_t)l * H * H,
            hout, Wout, bout, out, (l == NLAYERS - 1) ? 1 : 0);
    }
}